// Round 1
// baseline (678.123 us; speedup 1.0000x reference)
//
#include <hip/hip_runtime.h>
#include <stdint.h>

#define NTOK 65536          // B*T
#define DE 384
#define S_HEAD 25165824     // NTOK*DE elements (per q/k/v tensor)

typedef __bf16 bf16x8 __attribute__((ext_vector_type(8)));
typedef float  f32x4 __attribute__((ext_vector_type(4)));

__device__ __forceinline__ unsigned short f2bf(float f) {
  union { float fl; unsigned u; } a; a.fl = f;
  unsigned r = a.u + 0x7fffu + ((a.u >> 16) & 1u);
  return (unsigned short)(r >> 16);
}

__device__ __forceinline__ void gll16(const void* g, void* l) {
  __builtin_amdgcn_global_load_lds((const __attribute__((address_space(1))) void*)g,
                                   (__attribute__((address_space(3))) void*)l, 16, 0, 0);
}

// ---------------- weight packing ----------------
// dst[c*R + r] = bf16(src[r*C + c])   (B [K][N] f32 -> Bt [N][K] bf16)
__global__ void pack_t(unsigned short* __restrict__ dst, const float* __restrict__ src,
                       int R, int C) {
  int t = blockIdx.x * 256 + threadIdx.x;
  if (t >= R * C) return;
  int r = t / C, c = t - r * C;
  dst[(size_t)c * R + r] = f2bf(src[t]);
}

// wq/wk/wv [H=6][D=384][HS=64] f32 -> Wqkv_t [1152][384] bf16, n = which*384 + h*64 + e, k = d
__global__ void qkv_pack(const float* __restrict__ wq, const float* __restrict__ wk,
                         const float* __restrict__ wv, unsigned short* __restrict__ dst) {
  int t = blockIdx.x * 256 + threadIdx.x;
  if (t >= 3 * 147456) return;
  int which = t / 147456, r = t - which * 147456;
  const float* src = which == 0 ? wq : (which == 1 ? wk : wv);
  int h = r / 24576, r2 = r - h * 24576;
  int d = r2 >> 6, e = r2 & 63;
  dst[(size_t)(which * 384 + h * 64 + e) * 384 + d] = f2bf(src[r]);
}

// ---------------- layernorm (f32 in -> bf16 out), wave per row ----------------
__global__ __launch_bounds__(256) void ln_kernel(const float* __restrict__ x,
                                                 const float* __restrict__ g,
                                                 const float* __restrict__ be,
                                                 unsigned short* __restrict__ out) {
  int wave = threadIdx.x >> 6, lane = threadIdx.x & 63;
  size_t row = (size_t)blockIdx.x * 4 + wave;
  const float* xr = x + row * DE;
  int c0 = lane * 2;
  float2 v0 = *(const float2*)(xr + c0);
  float2 v1 = *(const float2*)(xr + 128 + c0);
  float2 v2 = *(const float2*)(xr + 256 + c0);
  float s  = v0.x + v0.y + v1.x + v1.y + v2.x + v2.y;
  float ss = v0.x*v0.x + v0.y*v0.y + v1.x*v1.x + v1.y*v1.y + v2.x*v2.x + v2.y*v2.y;
#pragma unroll
  for (int m = 1; m < 64; m <<= 1) { s += __shfl_xor(s, m); ss += __shfl_xor(ss, m); }
  float mu = s * (1.0f / 384.0f);
  float rstd = rsqrtf(ss * (1.0f / 384.0f) - mu * mu + 1e-5f);
  unsigned short* orow = out + row * DE;
  {
    float a0 = (v0.x - mu) * rstd * g[c0] + be[c0];
    float a1 = (v0.y - mu) * rstd * g[c0 + 1] + be[c0 + 1];
    *(unsigned*)(orow + c0) = (unsigned)f2bf(a0) | ((unsigned)f2bf(a1) << 16);
  }
  {
    int c = c0 + 128;
    float a0 = (v1.x - mu) * rstd * g[c] + be[c];
    float a1 = (v1.y - mu) * rstd * g[c + 1] + be[c + 1];
    *(unsigned*)(orow + c) = (unsigned)f2bf(a0) | ((unsigned)f2bf(a1) << 16);
  }
  {
    int c = c0 + 256;
    float a0 = (v2.x - mu) * rstd * g[c] + be[c];
    float a1 = (v2.y - mu) * rstd * g[c + 1] + be[c + 1];
    *(unsigned*)(orow + c) = (unsigned)f2bf(a0) | ((unsigned)f2bf(a1) << 16);
  }
}

// ---------------- GEMM: C[M,N] = A[M,K] @ Bt[N,K]^T, fused epilogues ----------------
// EPI 0: QKV scatter (outb = qkv base; q,k in [B,H,T,HS], v transposed [B,H,HS,T])
// EPI 1: outf = acc + bias[n] + resid   (proj -> x1, f32)
// EPI 2: outb = bf16(relu(acc + bias[n]))
// EPI 3: outf = acc + bias[n] + resid   (final out, f32)
template<int EPI>
__global__ __launch_bounds__(256)
void gemm_bt(const unsigned short* __restrict__ A, const unsigned short* __restrict__ Bt,
             int M, int N, int K,
             const float* __restrict__ bias, const float* __restrict__ resid,
             float* __restrict__ outf, unsigned short* __restrict__ outb) {
  __shared__ unsigned short As[128 * 32];
  __shared__ unsigned short Bs[128 * 32];
  const int tid = threadIdx.x;
  const int wave = tid >> 6, lane = tid & 63;
  const int mBase = blockIdx.y << 7, nBase = blockIdx.x << 7;
  const int wm = (wave >> 1) << 6, wn = (wave & 1) << 6;
  const int fr = lane & 15, fk = (lane >> 4) << 3;

  // staging: thread covers row tid/4 (and +64), 8 bf16 at col (tid%4)*8
  const int srow = tid >> 2, scol = (tid & 3) << 3;
  const unsigned short* ag = A + (size_t)(mBase + srow) * K + scol;
  const unsigned short* bg = Bt + (size_t)(nBase + srow) * K + scol;
  unsigned short* as0 = As + wave * (16 * 32);
  unsigned short* as1 = As + (64 + wave * 16) * 32;
  unsigned short* bs0 = Bs + wave * (16 * 32);
  unsigned short* bs1 = Bs + (64 + wave * 16) * 32;
  const size_t half = (size_t)64 * K;

  f32x4 acc[4][4];
  const f32x4 z = {0.f, 0.f, 0.f, 0.f};
#pragma unroll
  for (int i = 0; i < 4; ++i)
#pragma unroll
    for (int j = 0; j < 4; ++j) acc[i][j] = z;

  for (int kt = 0; kt < K; kt += 32) {
    gll16(ag + kt, as0);
    gll16(ag + half + kt, as1);
    gll16(bg + kt, bs0);
    gll16(bg + half + kt, bs1);
    __syncthreads();
    bf16x8 af[4], bfr[4];
#pragma unroll
    for (int mb = 0; mb < 4; ++mb) af[mb] = *(const bf16x8*)(As + (wm + mb * 16 + fr) * 32 + fk);
#pragma unroll
    for (int nb = 0; nb < 4; ++nb) bfr[nb] = *(const bf16x8*)(Bs + (wn + nb * 16 + fr) * 32 + fk);
#pragma unroll
    for (int mb = 0; mb < 4; ++mb)
#pragma unroll
      for (int nb = 0; nb < 4; ++nb)
        acc[mb][nb] = __builtin_amdgcn_mfma_f32_16x16x32_bf16(af[mb], bfr[nb], acc[mb][nb], 0, 0, 0);
    __syncthreads();
  }

#pragma unroll
  for (int mb = 0; mb < 4; ++mb) {
#pragma unroll
    for (int nb = 0; nb < 4; ++nb) {
      const int gn = nBase + wn + nb * 16 + fr;
#pragma unroll
      for (int i = 0; i < 4; ++i) {
        const int gm = mBase + wm + mb * 16 + ((lane >> 4) << 2) + i;
        float val = acc[mb][nb][i];
        if (EPI == 0) {
          int which = gn / 384;
          int rest = gn - which * 384;
          int hh = rest >> 6, e = rest & 63;
          int b = gm >> 8, t = gm & 255;
          size_t idx;
          if (which < 2)
            idx = (size_t)which * S_HEAD + (((size_t)(b * 6 + hh) * 256 + t) << 6) + e;
          else
            idx = 2 * (size_t)S_HEAD + (((size_t)(b * 6 + hh) * 64 + e) << 8) + t;
          outb[idx] = f2bf(val);
        } else if (EPI == 1) {
          size_t idx = (size_t)gm * N + gn;
          outf[idx] = val + bias[gn] + resid[idx];
        } else if (EPI == 2) {
          float r = val + bias[gn];
          outb[(size_t)gm * N + gn] = f2bf(r > 0.f ? r : 0.f);
        } else {
          size_t idx = (size_t)gm * N + gn;
          outf[idx] = val + bias[gn] + resid[idx];
        }
      }
    }
  }
}

// ---------------- attention: one block per (b,h), 4 waves x 64 Q-rows ----------------
__global__ __launch_bounds__(256)
void attn_kernel(const unsigned short* __restrict__ q, const unsigned short* __restrict__ kk,
                 const unsigned short* __restrict__ vt, unsigned short* __restrict__ o) {
  __shared__ unsigned short Pw[4][64 * 32];
  const int bh = blockIdx.x;
  const int b = bh / 6, h = bh - b * 6;
  const unsigned short* qb = q + (size_t)bh * 256 * 64;
  const unsigned short* kb = kk + (size_t)bh * 256 * 64;
  const unsigned short* vb = vt + (size_t)bh * 64 * 256;  // [feat][t]
  const int wave = threadIdx.x >> 6, lane = threadIdx.x & 63;
  const int fr = lane & 15, fg = lane >> 4;
  const int fk = fg << 3;
  const int qrow0 = wave << 6;
  const float scale = 0.051031036307982884f;  // 1/sqrt(384)
  const f32x4 z = {0.f, 0.f, 0.f, 0.f};

  bf16x8 qf[4][2];
#pragma unroll
  for (int rb = 0; rb < 4; ++rb)
#pragma unroll
    for (int ks = 0; ks < 2; ++ks)
      qf[rb][ks] = *(const bf16x8*)(qb + (qrow0 + rb * 16 + fr) * 64 + ks * 32 + fk);

  // pass 1: per-lane running max over this lane's columns
  float pm[4][4];
#pragma unroll
  for (int rb = 0; rb < 4; ++rb)
#pragma unroll
    for (int i = 0; i < 4; ++i) pm[rb][i] = -1e30f;

  for (int cb = 0; cb < 16; ++cb) {
    bf16x8 kf0 = *(const bf16x8*)(kb + (cb * 16 + fr) * 64 + fk);
    bf16x8 kf1 = *(const bf16x8*)(kb + (cb * 16 + fr) * 64 + 32 + fk);
#pragma unroll
    for (int rb = 0; rb < 4; ++rb) {
      f32x4 s = __builtin_amdgcn_mfma_f32_16x16x32_bf16(qf[rb][0], kf0, z, 0, 0, 0);
      s = __builtin_amdgcn_mfma_f32_16x16x32_bf16(qf[rb][1], kf1, s, 0, 0, 0);
#pragma unroll
      for (int i = 0; i < 4; ++i) pm[rb][i] = fmaxf(pm[rb][i], s[i]);
    }
  }
  // reduce max across the 16 lanes of each column-group
#pragma unroll
  for (int rb = 0; rb < 4; ++rb)
#pragma unroll
    for (int i = 0; i < 4; ++i) {
      float v = pm[rb][i];
      v = fmaxf(v, __shfl_xor(v, 1));
      v = fmaxf(v, __shfl_xor(v, 2));
      v = fmaxf(v, __shfl_xor(v, 4));
      v = fmaxf(v, __shfl_xor(v, 8));
      pm[rb][i] = v;
    }

  // pass 2: recompute S, exp, stage P per-wave, PV MFMA
  f32x4 oacc[4][4];
  float psum[4][4];
#pragma unroll
  for (int rb = 0; rb < 4; ++rb)
#pragma unroll
    for (int nb = 0; nb < 4; ++nb) oacc[rb][nb] = z;
#pragma unroll
  for (int rb = 0; rb < 4; ++rb)
#pragma unroll
    for (int i = 0; i < 4; ++i) psum[rb][i] = 0.f;

  for (int kb2 = 0; kb2 < 8; ++kb2) {
#pragma unroll
    for (int c2 = 0; c2 < 2; ++c2) {
      int cb = kb2 * 2 + c2;
      bf16x8 kf0 = *(const bf16x8*)(kb + (cb * 16 + fr) * 64 + fk);
      bf16x8 kf1 = *(const bf16x8*)(kb + (cb * 16 + fr) * 64 + 32 + fk);
#pragma unroll
      for (int rb = 0; rb < 4; ++rb) {
        f32x4 s = __builtin_amdgcn_mfma_f32_16x16x32_bf16(qf[rb][0], kf0, z, 0, 0, 0);
        s = __builtin_amdgcn_mfma_f32_16x16x32_bf16(qf[rb][1], kf1, s, 0, 0, 0);
#pragma unroll
        for (int i = 0; i < 4; ++i) {
          float p = __expf(scale * (s[i] - pm[rb][i]));
          psum[rb][i] += p;
          Pw[wave][(rb * 16 + (fg << 2) + i) * 32 + c2 * 16 + fr] = f2bf(p);
        }
      }
    }
    bf16x8 pa[4], vf[4];
#pragma unroll
    for (int rb = 0; rb < 4; ++rb) pa[rb] = *(const bf16x8*)(&Pw[wave][(rb * 16 + fr) * 32 + fk]);
#pragma unroll
    for (int nb = 0; nb < 4; ++nb)
      vf[nb] = *(const bf16x8*)(vb + (nb * 16 + fr) * 256 + kb2 * 32 + fk);
#pragma unroll
    for (int rb = 0; rb < 4; ++rb)
#pragma unroll
      for (int nb = 0; nb < 4; ++nb)
        oacc[rb][nb] = __builtin_amdgcn_mfma_f32_16x16x32_bf16(pa[rb], vf[nb], oacc[rb][nb], 0, 0, 0);
  }

  float rs[4][4];
#pragma unroll
  for (int rb = 0; rb < 4; ++rb)
#pragma unroll
    for (int i = 0; i < 4; ++i) {
      float v = psum[rb][i];
      v += __shfl_xor(v, 1);
      v += __shfl_xor(v, 2);
      v += __shfl_xor(v, 4);
      v += __shfl_xor(v, 8);
      rs[rb][i] = 1.0f / v;
    }

#pragma unroll
  for (int rb = 0; rb < 4; ++rb)
#pragma unroll
    for (int nb = 0; nb < 4; ++nb)
#pragma unroll
      for (int i = 0; i < 4; ++i) {
        int token = b * 256 + qrow0 + rb * 16 + (fg << 2) + i;
        int gcol = h * 64 + nb * 16 + fr;
        o[(size_t)token * DE + gcol] = f2bf(oacc[rb][nb][i] * rs[rb][i]);
      }
}

// ---------------- launch ----------------
extern "C" void kernel_launch(void* const* d_in, const int* in_sizes, int n_in,
                              void* d_out, int out_size, void* d_ws, size_t ws_size,
                              hipStream_t stream) {
  const float* x     = (const float*)d_in[0];
  const float* wq    = (const float*)d_in[1];
  const float* wk    = (const float*)d_in[2];
  const float* wv    = (const float*)d_in[3];
  const float* wproj = (const float*)d_in[4];
  const float* bproj = (const float*)d_in[5];
  const float* w1    = (const float*)d_in[6];
  const float* b1    = (const float*)d_in[7];
  const float* w2    = (const float*)d_in[8];
  const float* b2    = (const float*)d_in[9];
  const float* g1    = (const float*)d_in[10];
  const float* be1   = (const float*)d_in[11];
  const float* g2    = (const float*)d_in[12];
  const float* be2   = (const float*)d_in[13];

  char* ws = (char*)d_ws;
  // layout (bytes):
  // [0, 50331648)            xln bf16            (later reused as h)
  // [50331648, 251658240)    q|k|v bf16 (151MB) + attn_out bf16 (50MB)  (later reused as act)
  // [251658240, 352321536)   x1 f32
  // [352321536, ...)         packed weights
  unsigned short* xln   = (unsigned short*)(ws + 0);
  unsigned short* hbuf  = xln;
  unsigned short* qkv   = (unsigned short*)(ws + 50331648);
  unsigned short* attno = (unsigned short*)(ws + 201326592);
  unsigned short* act   = (unsigned short*)(ws + 50331648);
  float*          x1    = (float*)(ws + 251658240);
  unsigned short* wqkvt = (unsigned short*)(ws + 352321536);
  unsigned short* wprjt = (unsigned short*)(ws + 352321536 + 884736);
  unsigned short* w1t   = (unsigned short*)(ws + 352321536 + 884736 + 294912);
  unsigned short* w2t   = (unsigned short*)(ws + 352321536 + 884736 + 294912 + 1179648);

  qkv_pack<<<(3 * 147456 + 255) / 256, 256, 0, stream>>>(wq, wk, wv, wqkvt);
  pack_t<<<(147456 + 255) / 256, 256, 0, stream>>>(wprjt, wproj, 384, 384);
  pack_t<<<(589824 + 255) / 256, 256, 0, stream>>>(w1t, w1, 384, 1536);
  pack_t<<<(589824 + 255) / 256, 256, 0, stream>>>(w2t, w2, 1536, 384);

  ln_kernel<<<NTOK / 4, 256, 0, stream>>>(x, g1, be1, xln);

  gemm_bt<0><<<dim3(9, 512), 256, 0, stream>>>(xln, wqkvt, NTOK, 1152, 384,
                                               nullptr, nullptr, nullptr, qkv);

  attn_kernel<<<1536, 256, 0, stream>>>(qkv, qkv + S_HEAD, qkv + 2 * (size_t)S_HEAD, attno);

  gemm_bt<1><<<dim3(3, 512), 256, 0, stream>>>(attno, wprjt, NTOK, 384, 384,
                                               bproj, x, x1, nullptr);

  ln_kernel<<<NTOK / 4, 256, 0, stream>>>(x1, g2, be2, hbuf);

  gemm_bt<2><<<dim3(12, 512), 256, 0, stream>>>(hbuf, w1t, NTOK, 1536, 384,
                                                b1, nullptr, nullptr, act);

  gemm_bt<3><<<dim3(3, 512), 256, 0, stream>>>(act, w2t, NTOK, 384, 1536,
                                               b2, x1, (float*)d_out, nullptr);
}

// Round 2
// 673.320 us; speedup vs baseline: 1.0071x; 1.0071x over previous
//
#include <hip/hip_runtime.h>
#include <stdint.h>

#define NTOK 65536          // B*T
#define DE 384
#define S_HEAD 25165824     // NTOK*DE elements (per q/k/v tensor)

typedef __bf16 bf16x8 __attribute__((ext_vector_type(8)));
typedef float  f32x4 __attribute__((ext_vector_type(4)));

__device__ __forceinline__ unsigned short f2bf(float f) {
  union { float fl; unsigned u; } a; a.fl = f;
  unsigned r = a.u + 0x7fffu + ((a.u >> 16) & 1u);
  return (unsigned short)(r >> 16);
}

__device__ __forceinline__ void gll16(const void* g, void* l) {
  __builtin_amdgcn_global_load_lds((const __attribute__((address_space(1))) void*)g,
                                   (__attribute__((address_space(3))) void*)l, 16, 0, 0);
}

// ---------------- weight packing ----------------
__global__ void pack_t(unsigned short* __restrict__ dst, const float* __restrict__ src,
                       int R, int C) {
  int t = blockIdx.x * 256 + threadIdx.x;
  if (t >= R * C) return;
  int r = t / C, c = t - r * C;
  dst[(size_t)c * R + r] = f2bf(src[t]);
}

__global__ void qkv_pack(const float* __restrict__ wq, const float* __restrict__ wk,
                         const float* __restrict__ wv, unsigned short* __restrict__ dst) {
  int t = blockIdx.x * 256 + threadIdx.x;
  if (t >= 3 * 147456) return;
  int which = t / 147456, r = t - which * 147456;
  const float* src = which == 0 ? wq : (which == 1 ? wk : wv);
  int h = r / 24576, r2 = r - h * 24576;
  int d = r2 >> 6, e = r2 & 63;
  dst[(size_t)(which * 384 + h * 64 + e) * 384 + d] = f2bf(src[r]);
}

// ---------------- layernorm (f32 in -> bf16 out), wave per row ----------------
__global__ __launch_bounds__(256) void ln_kernel(const float* __restrict__ x,
                                                 const float* __restrict__ g,
                                                 const float* __restrict__ be,
                                                 unsigned short* __restrict__ out) {
  int wave = threadIdx.x >> 6, lane = threadIdx.x & 63;
  size_t row = (size_t)blockIdx.x * 4 + wave;
  const float* xr = x + row * DE;
  int c0 = lane * 2;
  float2 v0 = *(const float2*)(xr + c0);
  float2 v1 = *(const float2*)(xr + 128 + c0);
  float2 v2 = *(const float2*)(xr + 256 + c0);
  float s  = v0.x + v0.y + v1.x + v1.y + v2.x + v2.y;
  float ss = v0.x*v0.x + v0.y*v0.y + v1.x*v1.x + v1.y*v1.y + v2.x*v2.x + v2.y*v2.y;
#pragma unroll
  for (int m = 1; m < 64; m <<= 1) { s += __shfl_xor(s, m); ss += __shfl_xor(ss, m); }
  float mu = s * (1.0f / 384.0f);
  float rstd = rsqrtf(ss * (1.0f / 384.0f) - mu * mu + 1e-5f);
  unsigned short* orow = out + row * DE;
  {
    float a0 = (v0.x - mu) * rstd * g[c0] + be[c0];
    float a1 = (v0.y - mu) * rstd * g[c0 + 1] + be[c0 + 1];
    *(unsigned*)(orow + c0) = (unsigned)f2bf(a0) | ((unsigned)f2bf(a1) << 16);
  }
  {
    int c = c0 + 128;
    float a0 = (v1.x - mu) * rstd * g[c] + be[c];
    float a1 = (v1.y - mu) * rstd * g[c + 1] + be[c + 1];
    *(unsigned*)(orow + c) = (unsigned)f2bf(a0) | ((unsigned)f2bf(a1) << 16);
  }
  {
    int c = c0 + 256;
    float a0 = (v2.x - mu) * rstd * g[c] + be[c];
    float a1 = (v2.y - mu) * rstd * g[c + 1] + be[c + 1];
    *(unsigned*)(orow + c) = (unsigned)f2bf(a0) | ((unsigned)f2bf(a1) << 16);
  }
}

// ---------------- GEMM: C[M,N] = A[M,K] @ Bt[N,K]^T ----------------
// 256x128 tile, BK=64, 8 waves (4M x 2N), per-wave 64x64, dbuf LDS + T2 swizzle.
// EPI 0: QKV scatter; EPI 1/3: outf = acc+bias+resid (f32); EPI 2: outb = bf16(relu(acc+bias))
template<int EPI>
__global__ __launch_bounds__(512, 2)
void gemm_bt(const unsigned short* __restrict__ A, const unsigned short* __restrict__ Bt,
             int M, int N, int K, int ntx,
             const float* __restrict__ bias, const float* __restrict__ resid,
             float* __restrict__ outf, unsigned short* __restrict__ outb) {
  __shared__ __align__(16) unsigned short As[2][16384];   // 256 rows x 64 cols (swizzled)
  __shared__ __align__(16) unsigned short Bs[2][8192];    // 128 rows x 64 cols (swizzled)
  const int tid = threadIdx.x;
  const int wave = tid >> 6, lane = tid & 63;

  // XCD-chunked swizzle: contiguous wg chunk per XCD; x-fastest -> same-A blocks share L2
  const int nwg = gridDim.x;
  const int cpx = nwg >> 3;
  const int wg = (blockIdx.x & 7) * cpx + (blockIdx.x >> 3);
  const int bx = wg % ntx, by = wg / ntx;
  const int mBase = by << 8, nBase = bx << 7;
  const int wm = (wave >> 1) << 6, wn = (wave & 1) << 6;
  const int fr = lane & 15, fg = lane >> 4, fk = fg << 3;

  f32x4 acc[4][4];
  const f32x4 z = {0.f, 0.f, 0.f, 0.f};
#pragma unroll
  for (int i = 0; i < 4; ++i)
#pragma unroll
    for (int j = 0; j < 4; ++j) acc[i][j] = z;

  // stage one K-tile (BK=64) into buffer buf: linear LDS dest, inverse-swizzled source
  auto stage = [&](int buf, int kt) {
#pragma unroll
    for (int i = 0; i < 4; ++i) {       // A: 32 KB = 4 rounds x 8 KB
      int Lb = i * 8192 + wave * 1024;  // wave-uniform LDS byte base
      int L = Lb + lane * 16;
      int row = L >> 7;
      int col = (((L >> 4) & 7) ^ (row & 7)) << 3;
      gll16(A + (size_t)(mBase + row) * K + kt + col, (unsigned short*)As[buf] + (Lb >> 1));
    }
#pragma unroll
    for (int i = 0; i < 2; ++i) {       // B: 16 KB = 2 rounds x 8 KB
      int Lb = i * 8192 + wave * 1024;
      int L = Lb + lane * 16;
      int row = L >> 7;
      int col = (((L >> 4) & 7) ^ (row & 7)) << 3;
      gll16(Bt + (size_t)(nBase + row) * K + kt + col, (unsigned short*)Bs[buf] + (Lb >> 1));
    }
  };

  const int NK = K >> 6;
  stage(0, 0);
  for (int t = 0; t < NK; ++t) {
    const int cur = t & 1;
    if (t + 1 < NK) {
      stage(cur ^ 1, (t + 1) << 6);
      asm volatile("s_waitcnt vmcnt(6)" ::: "memory");   // this tile's 6 loads done; next 6 in flight
    } else {
      asm volatile("s_waitcnt vmcnt(0)" ::: "memory");
    }
    __builtin_amdgcn_sched_barrier(0);
    __builtin_amdgcn_s_barrier();
    __builtin_amdgcn_sched_barrier(0);

    const unsigned short* as = As[cur];
    const unsigned short* bs = Bs[cur];
    bf16x8 af[2][4], bfr[2][4];
#pragma unroll
    for (int ks = 0; ks < 2; ++ks) {
#pragma unroll
      for (int mb = 0; mb < 4; ++mb) {
        int row = wm + mb * 16 + fr;
        int byte = (row << 7) + (((ks * 4 + fg) ^ (row & 7)) << 4);
        af[ks][mb] = *(const bf16x8*)((const char*)as + byte);
      }
#pragma unroll
      for (int nb = 0; nb < 4; ++nb) {
        int row = wn + nb * 16 + fr;
        int byte = (row << 7) + (((ks * 4 + fg) ^ (row & 7)) << 4);
        bfr[ks][nb] = *(const bf16x8*)((const char*)bs + byte);
      }
    }
    __builtin_amdgcn_s_setprio(1);
#pragma unroll
    for (int ks = 0; ks < 2; ++ks)
#pragma unroll
      for (int mb = 0; mb < 4; ++mb)
#pragma unroll
        for (int nb = 0; nb < 4; ++nb)
          acc[mb][nb] = __builtin_amdgcn_mfma_f32_16x16x32_bf16(af[ks][mb], bfr[ks][nb], acc[mb][nb], 0, 0, 0);
    __builtin_amdgcn_s_setprio(0);
    __builtin_amdgcn_sched_barrier(0);
    __builtin_amdgcn_s_barrier();   // all waves done reading buf cur before it is restaged
    __builtin_amdgcn_sched_barrier(0);
  }

#pragma unroll
  for (int mb = 0; mb < 4; ++mb) {
#pragma unroll
    for (int nb = 0; nb < 4; ++nb) {
      const int gn = nBase + wn + nb * 16 + fr;
#pragma unroll
      for (int i = 0; i < 4; ++i) {
        const int gm = mBase + wm + mb * 16 + (fg << 2) + i;
        float val = acc[mb][nb][i];
        if (EPI == 0) {
          int which = gn / 384;
          int rest = gn - which * 384;
          int hh = rest >> 6, e = rest & 63;
          int b = gm >> 8, tt = gm & 255;
          size_t idx;
          if (which < 2)
            idx = (size_t)which * S_HEAD + (((size_t)(b * 6 + hh) * 256 + tt) << 6) + e;
          else
            idx = 2 * (size_t)S_HEAD + (((size_t)(b * 6 + hh) * 64 + e) << 8) + tt;
          outb[idx] = f2bf(val);
        } else if (EPI == 1) {
          size_t idx = (size_t)gm * N + gn;
          outf[idx] = val + bias[gn] + resid[idx];
        } else if (EPI == 2) {
          float r = val + bias[gn];
          outb[(size_t)gm * N + gn] = f2bf(r > 0.f ? r : 0.f);
        } else {
          size_t idx = (size_t)gm * N + gn;
          outf[idx] = val + bias[gn] + resid[idx];
        }
      }
    }
  }
}

// ---------------- attention: one block per (b,h), 4 waves x 64 Q-rows ----------------
__global__ __launch_bounds__(256)
void attn_kernel(const unsigned short* __restrict__ q, const unsigned short* __restrict__ kk,
                 const unsigned short* __restrict__ vt, unsigned short* __restrict__ o) {
  __shared__ unsigned short Pw[4][64 * 32];
  const int bh = blockIdx.x;
  const int b = bh / 6, h = bh - b * 6;
  const unsigned short* qb = q + (size_t)bh * 256 * 64;
  const unsigned short* kb = kk + (size_t)bh * 256 * 64;
  const unsigned short* vb = vt + (size_t)bh * 64 * 256;  // [feat][t]
  const int wave = threadIdx.x >> 6, lane = threadIdx.x & 63;
  const int fr = lane & 15, fg = lane >> 4;
  const int fk = fg << 3;
  const int qrow0 = wave << 6;
  const float scale = 0.051031036307982884f;  // 1/sqrt(384)
  const f32x4 z = {0.f, 0.f, 0.f, 0.f};

  bf16x8 qf[4][2];
#pragma unroll
  for (int rb = 0; rb < 4; ++rb)
#pragma unroll
    for (int ks = 0; ks < 2; ++ks)
      qf[rb][ks] = *(const bf16x8*)(qb + (qrow0 + rb * 16 + fr) * 64 + ks * 32 + fk);

  float pm[4][4];
#pragma unroll
  for (int rb = 0; rb < 4; ++rb)
#pragma unroll
    for (int i = 0; i < 4; ++i) pm[rb][i] = -1e30f;

  for (int cb = 0; cb < 16; ++cb) {
    bf16x8 kf0 = *(const bf16x8*)(kb + (cb * 16 + fr) * 64 + fk);
    bf16x8 kf1 = *(const bf16x8*)(kb + (cb * 16 + fr) * 64 + 32 + fk);
#pragma unroll
    for (int rb = 0; rb < 4; ++rb) {
      f32x4 s = __builtin_amdgcn_mfma_f32_16x16x32_bf16(qf[rb][0], kf0, z, 0, 0, 0);
      s = __builtin_amdgcn_mfma_f32_16x16x32_bf16(qf[rb][1], kf1, s, 0, 0, 0);
#pragma unroll
      for (int i = 0; i < 4; ++i) pm[rb][i] = fmaxf(pm[rb][i], s[i]);
    }
  }
#pragma unroll
  for (int rb = 0; rb < 4; ++rb)
#pragma unroll
    for (int i = 0; i < 4; ++i) {
      float v = pm[rb][i];
      v = fmaxf(v, __shfl_xor(v, 1));
      v = fmaxf(v, __shfl_xor(v, 2));
      v = fmaxf(v, __shfl_xor(v, 4));
      v = fmaxf(v, __shfl_xor(v, 8));
      pm[rb][i] = v;
    }

  f32x4 oacc[4][4];
  float psum[4][4];
#pragma unroll
  for (int rb = 0; rb < 4; ++rb)
#pragma unroll
    for (int nb = 0; nb < 4; ++nb) oacc[rb][nb] = z;
#pragma unroll
  for (int rb = 0; rb < 4; ++rb)
#pragma unroll
    for (int i = 0; i < 4; ++i) psum[rb][i] = 0.f;

  for (int kb2 = 0; kb2 < 8; ++kb2) {
#pragma unroll
    for (int c2 = 0; c2 < 2; ++c2) {
      int cb = kb2 * 2 + c2;
      bf16x8 kf0 = *(const bf16x8*)(kb + (cb * 16 + fr) * 64 + fk);
      bf16x8 kf1 = *(const bf16x8*)(kb + (cb * 16 + fr) * 64 + 32 + fk);
#pragma unroll
      for (int rb = 0; rb < 4; ++rb) {
        f32x4 s = __builtin_amdgcn_mfma_f32_16x16x32_bf16(qf[rb][0], kf0, z, 0, 0, 0);
        s = __builtin_amdgcn_mfma_f32_16x16x32_bf16(qf[rb][1], kf1, s, 0, 0, 0);
#pragma unroll
        for (int i = 0; i < 4; ++i) {
          float p = __expf(scale * (s[i] - pm[rb][i]));
          psum[rb][i] += p;
          Pw[wave][(rb * 16 + (fg << 2) + i) * 32 + c2 * 16 + fr] = f2bf(p);
        }
      }
    }
    bf16x8 pa[4], vf[4];
#pragma unroll
    for (int rb = 0; rb < 4; ++rb) pa[rb] = *(const bf16x8*)(&Pw[wave][(rb * 16 + fr) * 32 + fk]);
#pragma unroll
    for (int nb = 0; nb < 4; ++nb)
      vf[nb] = *(const bf16x8*)(vb + (nb * 16 + fr) * 256 + kb2 * 32 + fk);
#pragma unroll
    for (int rb = 0; rb < 4; ++rb)
#pragma unroll
      for (int nb = 0; nb < 4; ++nb)
        oacc[rb][nb] = __builtin_amdgcn_mfma_f32_16x16x32_bf16(pa[rb], vf[nb], oacc[rb][nb], 0, 0, 0);
  }

  float rs[4][4];
#pragma unroll
  for (int rb = 0; rb < 4; ++rb)
#pragma unroll
    for (int i = 0; i < 4; ++i) {
      float v = psum[rb][i];
      v += __shfl_xor(v, 1);
      v += __shfl_xor(v, 2);
      v += __shfl_xor(v, 4);
      v += __shfl_xor(v, 8);
      rs[rb][i] = 1.0f / v;
    }

#pragma unroll
  for (int rb = 0; rb < 4; ++rb)
#pragma unroll
    for (int nb = 0; nb < 4; ++nb)
#pragma unroll
      for (int i = 0; i < 4; ++i) {
        int token = b * 256 + qrow0 + rb * 16 + (fg << 2) + i;
        int gcol = h * 64 + nb * 16 + fr;
        o[(size_t)token * DE + gcol] = f2bf(oacc[rb][nb][i] * rs[rb][i]);
      }
}

// ---------------- launch ----------------
extern "C" void kernel_launch(void* const* d_in, const int* in_sizes, int n_in,
                              void* d_out, int out_size, void* d_ws, size_t ws_size,
                              hipStream_t stream) {
  const float* x     = (const float*)d_in[0];
  const float* wq    = (const float*)d_in[1];
  const float* wk    = (const float*)d_in[2];
  const float* wv    = (const float*)d_in[3];
  const float* wproj = (const float*)d_in[4];
  const float* bproj = (const float*)d_in[5];
  const float* w1    = (const float*)d_in[6];
  const float* b1    = (const float*)d_in[7];
  const float* w2    = (const float*)d_in[8];
  const float* b2    = (const float*)d_in[9];
  const float* g1    = (const float*)d_in[10];
  const float* be1   = (const float*)d_in[11];
  const float* g2    = (const float*)d_in[12];
  const float* be2   = (const float*)d_in[13];

  char* ws = (char*)d_ws;
  unsigned short* xln   = (unsigned short*)(ws + 0);
  unsigned short* hbuf  = xln;
  unsigned short* qkv   = (unsigned short*)(ws + 50331648);
  unsigned short* attno = (unsigned short*)(ws + 201326592);
  unsigned short* act   = (unsigned short*)(ws + 50331648);
  float*          x1    = (float*)(ws + 251658240);
  unsigned short* wqkvt = (unsigned short*)(ws + 352321536);
  unsigned short* wprjt = (unsigned short*)(ws + 352321536 + 884736);
  unsigned short* w1t   = (unsigned short*)(ws + 352321536 + 884736 + 294912);
  unsigned short* w2t   = (unsigned short*)(ws + 352321536 + 884736 + 294912 + 1179648);

  qkv_pack<<<(3 * 147456 + 255) / 256, 256, 0, stream>>>(wq, wk, wv, wqkvt);
  pack_t<<<(147456 + 255) / 256, 256, 0, stream>>>(wprjt, wproj, 384, 384);
  pack_t<<<(589824 + 255) / 256, 256, 0, stream>>>(w1t, w1, 384, 1536);
  pack_t<<<(589824 + 255) / 256, 256, 0, stream>>>(w2t, w2, 1536, 384);

  ln_kernel<<<NTOK / 4, 256, 0, stream>>>(x, g1, be1, xln);

  // grids: (N/128) * (M/256), all divisible by 8
  gemm_bt<0><<<9 * 256, 512, 0, stream>>>(xln, wqkvt, NTOK, 1152, 384, 9,
                                          nullptr, nullptr, nullptr, qkv);

  attn_kernel<<<1536, 256, 0, stream>>>(qkv, qkv + S_HEAD, qkv + 2 * (size_t)S_HEAD, attno);

  gemm_bt<1><<<3 * 256, 512, 0, stream>>>(attno, wprjt, NTOK, 384, 384, 3,
                                          bproj, x, x1, nullptr);

  ln_kernel<<<NTOK / 4, 256, 0, stream>>>(x1, g2, be2, hbuf);

  gemm_bt<2><<<12 * 256, 512, 0, stream>>>(hbuf, w1t, NTOK, 1536, 384, 12,
                                           b1, nullptr, nullptr, act);

  gemm_bt<3><<<3 * 256, 512, 0, stream>>>(act, w2t, NTOK, 384, 1536, 3,
                                          b2, x1, (float*)d_out, nullptr);
}

// Round 3
// 583.951 us; speedup vs baseline: 1.1613x; 1.1530x over previous
//
#include <hip/hip_runtime.h>
#include <stdint.h>

#define NTOK 65536          // B*T
#define DE 384
#define S_HEAD 25165824     // NTOK*DE elements (per q/k/v tensor)

typedef __bf16 bf16x8 __attribute__((ext_vector_type(8)));
typedef float  f32x4 __attribute__((ext_vector_type(4)));

__device__ __forceinline__ unsigned short f2bf(float f) {
  union { float fl; unsigned u; } a; a.fl = f;
  unsigned r = a.u + 0x7fffu + ((a.u >> 16) & 1u);
  return (unsigned short)(r >> 16);
}

__device__ __forceinline__ void gll16(const void* g, void* l) {
  __builtin_amdgcn_global_load_lds((const __attribute__((address_space(1))) void*)g,
                                   (__attribute__((address_space(3))) void*)l, 16, 0, 0);
}

__device__ __forceinline__ bf16x8 ds128(unsigned addr) {
  bf16x8 r;
  asm volatile("ds_read_b128 %0, %1" : "=v"(r) : "v"(addr));
  return r;
}

// ---------------- weight packing ----------------
__global__ void pack_t(unsigned short* __restrict__ dst, const float* __restrict__ src,
                       int R, int C) {
  int t = blockIdx.x * 256 + threadIdx.x;
  if (t >= R * C) return;
  int r = t / C, c = t - r * C;
  dst[(size_t)c * R + r] = f2bf(src[t]);
}

__global__ void qkv_pack(const float* __restrict__ wq, const float* __restrict__ wk,
                         const float* __restrict__ wv, unsigned short* __restrict__ dst) {
  int t = blockIdx.x * 256 + threadIdx.x;
  if (t >= 3 * 147456) return;
  int which = t / 147456, r = t - which * 147456;
  const float* src = which == 0 ? wq : (which == 1 ? wk : wv);
  int h = r / 24576, r2 = r - h * 24576;
  int d = r2 >> 6, e = r2 & 63;
  dst[(size_t)(which * 384 + h * 64 + e) * 384 + d] = f2bf(src[r]);
}

// ---------------- layernorm (f32 in -> bf16 out), wave per row ----------------
__global__ __launch_bounds__(256) void ln_kernel(const float* __restrict__ x,
                                                 const float* __restrict__ g,
                                                 const float* __restrict__ be,
                                                 unsigned short* __restrict__ out) {
  int wave = threadIdx.x >> 6, lane = threadIdx.x & 63;
  size_t row = (size_t)blockIdx.x * 4 + wave;
  const float* xr = x + row * DE;
  int c0 = lane * 2;
  float2 v0 = *(const float2*)(xr + c0);
  float2 v1 = *(const float2*)(xr + 128 + c0);
  float2 v2 = *(const float2*)(xr + 256 + c0);
  float s  = v0.x + v0.y + v1.x + v1.y + v2.x + v2.y;
  float ss = v0.x*v0.x + v0.y*v0.y + v1.x*v1.x + v1.y*v1.y + v2.x*v2.x + v2.y*v2.y;
#pragma unroll
  for (int m = 1; m < 64; m <<= 1) { s += __shfl_xor(s, m); ss += __shfl_xor(ss, m); }
  float mu = s * (1.0f / 384.0f);
  float rstd = rsqrtf(ss * (1.0f / 384.0f) - mu * mu + 1e-5f);
  unsigned short* orow = out + row * DE;
  {
    float a0 = (v0.x - mu) * rstd * g[c0] + be[c0];
    float a1 = (v0.y - mu) * rstd * g[c0 + 1] + be[c0 + 1];
    *(unsigned*)(orow + c0) = (unsigned)f2bf(a0) | ((unsigned)f2bf(a1) << 16);
  }
  {
    int c = c0 + 128;
    float a0 = (v1.x - mu) * rstd * g[c] + be[c];
    float a1 = (v1.y - mu) * rstd * g[c + 1] + be[c + 1];
    *(unsigned*)(orow + c) = (unsigned)f2bf(a0) | ((unsigned)f2bf(a1) << 16);
  }
  {
    int c = c0 + 256;
    float a0 = (v2.x - mu) * rstd * g[c] + be[c];
    float a1 = (v2.y - mu) * rstd * g[c + 1] + be[c + 1];
    *(unsigned*)(orow + c) = (unsigned)f2bf(a0) | ((unsigned)f2bf(a1) << 16);
  }
}

// ---------------- GEMM core: C[M,N] = A[M,K] @ Bt[N,K]^T ----------------
// 128x128 tile, BK=64, 4 waves (2x2), wave-tile 64x64, dbuf LDS (64KB -> 2 blocks/CU),
// T2 swizzle, counted vmcnt, asm ds_read fragments (no compiler vmcnt drain).
template<int EPI>
__device__ __forceinline__
void gemm_core(const unsigned short* __restrict__ A, const unsigned short* __restrict__ Bt,
               int M, int N, int K, int ntx,
               const float* __restrict__ bias, const float* __restrict__ resid,
               float* __restrict__ outf, unsigned short* __restrict__ outb) {
  __shared__ __align__(16) unsigned short As[2][8192];   // 128 rows x 64 cols, swizzled
  __shared__ __align__(16) unsigned short Bs[2][8192];
  const int tid = threadIdx.x;
  const int wave = tid >> 6, lane = tid & 63;

  const int nwg = gridDim.x;
  const int cpx = nwg >> 3;
  const int wg = (blockIdx.x & 7) * cpx + (blockIdx.x >> 3);
  const int bx = wg % ntx, by = wg / ntx;
  const int mBase = by << 7, nBase = bx << 7;
  const int wm = (wave >> 1) << 6, wn = (wave & 1) << 6;
  const int fr = lane & 15, fg = lane >> 4;

  const unsigned asb = (unsigned)(uintptr_t)&As[0][0];
  const unsigned bsb = (unsigned)(uintptr_t)&Bs[0][0];

  f32x4 acc[4][4];
  const f32x4 z = {0.f, 0.f, 0.f, 0.f};
#pragma unroll
  for (int i = 0; i < 4; ++i)
#pragma unroll
    for (int j = 0; j < 4; ++j) acc[i][j] = z;

  // stage K-tile: linear LDS dest, inverse-swizzled global source. 8 loads/thread.
  auto stage = [&](int buf, int kt) {
#pragma unroll
    for (int i = 0; i < 4; ++i) {
      int Lb = i * 4096 + wave * 1024;
      int L = Lb + lane * 16;
      int row = L >> 7;
      int col = (((L >> 4) & 7) ^ (row & 7)) << 3;
      gll16(A + (size_t)(mBase + row) * K + kt + col, (unsigned short*)As[buf] + (Lb >> 1));
    }
#pragma unroll
    for (int i = 0; i < 4; ++i) {
      int Lb = i * 4096 + wave * 1024;
      int L = Lb + lane * 16;
      int row = L >> 7;
      int col = (((L >> 4) & 7) ^ (row & 7)) << 3;
      gll16(Bt + (size_t)(nBase + row) * K + kt + col, (unsigned short*)Bs[buf] + (Lb >> 1));
    }
  };

  const int NK = K >> 6;
  stage(0, 0);
  for (int t = 0; t < NK; ++t) {
    const int cur = t & 1;
    if (t + 1 < NK) {
      stage(cur ^ 1, (t + 1) << 6);
      asm volatile("s_waitcnt vmcnt(8)" ::: "memory");   // this tile's 8 landed; next 8 in flight
    } else {
      asm volatile("s_waitcnt vmcnt(0)" ::: "memory");
    }
    asm volatile("" ::: "memory");
    __builtin_amdgcn_s_barrier();
    asm volatile("" ::: "memory");

    const unsigned ab = asb + (cur ? 16384u : 0u);
    const unsigned bb = bsb + (cur ? 16384u : 0u);
    bf16x8 af[2][4], bfr[2][4];
#pragma unroll
    for (int ks = 0; ks < 2; ++ks) {
#pragma unroll
      for (int mb = 0; mb < 4; ++mb) {
        int row = wm + mb * 16 + fr;
        unsigned byte = (unsigned)(row << 7) + ((unsigned)((ks * 4 + fg) ^ (row & 7)) << 4);
        af[ks][mb] = ds128(ab + byte);
      }
#pragma unroll
      for (int nb = 0; nb < 4; ++nb) {
        int row = wn + nb * 16 + fr;
        unsigned byte = (unsigned)(row << 7) + ((unsigned)((ks * 4 + fg) ^ (row & 7)) << 4);
        bfr[ks][nb] = ds128(bb + byte);
      }
    }
    asm volatile("s_waitcnt lgkmcnt(0)" ::: "memory");
    __builtin_amdgcn_sched_barrier(0);
    __builtin_amdgcn_s_setprio(1);
#pragma unroll
    for (int ks = 0; ks < 2; ++ks)
#pragma unroll
      for (int mb = 0; mb < 4; ++mb)
#pragma unroll
        for (int nb = 0; nb < 4; ++nb)
          acc[mb][nb] = __builtin_amdgcn_mfma_f32_16x16x32_bf16(af[ks][mb], bfr[ks][nb], acc[mb][nb], 0, 0, 0);
    __builtin_amdgcn_s_setprio(0);
    asm volatile("" ::: "memory");
    __builtin_amdgcn_s_barrier();   // all waves done reading buf cur before restage
    asm volatile("" ::: "memory");
  }

#pragma unroll
  for (int mb = 0; mb < 4; ++mb) {
#pragma unroll
    for (int nb = 0; nb < 4; ++nb) {
      const int gn = nBase + wn + nb * 16 + fr;
#pragma unroll
      for (int i = 0; i < 4; ++i) {
        const int gm = mBase + wm + mb * 16 + (fg << 2) + i;
        float val = acc[mb][nb][i];
        if (EPI == 0) {
          int which = gn / 384;
          int rest = gn - which * 384;
          int hh = rest >> 6, e = rest & 63;
          int b = gm >> 8, tt = gm & 255;
          size_t idx;
          if (which < 2)
            idx = (size_t)which * S_HEAD + (((size_t)(b * 6 + hh) * 256 + tt) << 6) + e;
          else
            idx = 2 * (size_t)S_HEAD + (((size_t)(b * 6 + hh) * 64 + e) << 8) + tt;
          outb[idx] = f2bf(val);
        } else if (EPI == 1) {
          size_t idx = (size_t)gm * N + gn;
          outf[idx] = val + bias[gn] + resid[idx];
        } else if (EPI == 2) {
          float r = val + bias[gn];
          outb[(size_t)gm * N + gn] = f2bf(r > 0.f ? r : 0.f);
        } else {
          size_t idx = (size_t)gm * N + gn;
          outf[idx] = val + bias[gn] + resid[idx];
        }
      }
    }
  }
}

__global__ __launch_bounds__(256, 2)
void gemm_qkv(const unsigned short* __restrict__ A, const unsigned short* __restrict__ Bt,
              int M, int N, int K, int ntx, const float* __restrict__ bias,
              const float* __restrict__ resid, float* __restrict__ outf,
              unsigned short* __restrict__ outb) {
  gemm_core<0>(A, Bt, M, N, K, ntx, bias, resid, outf, outb);
}
__global__ __launch_bounds__(256, 2)
void gemm_proj(const unsigned short* __restrict__ A, const unsigned short* __restrict__ Bt,
               int M, int N, int K, int ntx, const float* __restrict__ bias,
               const float* __restrict__ resid, float* __restrict__ outf,
               unsigned short* __restrict__ outb) {
  gemm_core<1>(A, Bt, M, N, K, ntx, bias, resid, outf, outb);
}
__global__ __launch_bounds__(256, 2)
void gemm_mlp1(const unsigned short* __restrict__ A, const unsigned short* __restrict__ Bt,
               int M, int N, int K, int ntx, const float* __restrict__ bias,
               const float* __restrict__ resid, float* __restrict__ outf,
               unsigned short* __restrict__ outb) {
  gemm_core<2>(A, Bt, M, N, K, ntx, bias, resid, outf, outb);
}
__global__ __launch_bounds__(256, 2)
void gemm_mlp2(const unsigned short* __restrict__ A, const unsigned short* __restrict__ Bt,
               int M, int N, int K, int ntx, const float* __restrict__ bias,
               const float* __restrict__ resid, float* __restrict__ outf,
               unsigned short* __restrict__ outb) {
  gemm_core<3>(A, Bt, M, N, K, ntx, bias, resid, outf, outb);
}

// ---------------- attention: one block per (b,h), 4 waves x 64 Q-rows ----------------
__global__ __launch_bounds__(256)
void attn_kernel(const unsigned short* __restrict__ q, const unsigned short* __restrict__ kk,
                 const unsigned short* __restrict__ vt, unsigned short* __restrict__ o) {
  __shared__ unsigned short Pw[4][64 * 32];
  const int bh = blockIdx.x;
  const int b = bh / 6, h = bh - b * 6;
  const unsigned short* qb = q + (size_t)bh * 256 * 64;
  const unsigned short* kb = kk + (size_t)bh * 256 * 64;
  const unsigned short* vb = vt + (size_t)bh * 64 * 256;  // [feat][t]
  const int wave = threadIdx.x >> 6, lane = threadIdx.x & 63;
  const int fr = lane & 15, fg = lane >> 4;
  const int fk = fg << 3;
  const int qrow0 = wave << 6;
  const float scale = 0.051031036307982884f;  // 1/sqrt(384)
  const f32x4 z = {0.f, 0.f, 0.f, 0.f};

  bf16x8 qf[4][2];
#pragma unroll
  for (int rb = 0; rb < 4; ++rb)
#pragma unroll
    for (int ks = 0; ks < 2; ++ks)
      qf[rb][ks] = *(const bf16x8*)(qb + (qrow0 + rb * 16 + fr) * 64 + ks * 32 + fk);

  float pm[4][4];
#pragma unroll
  for (int rb = 0; rb < 4; ++rb)
#pragma unroll
    for (int i = 0; i < 4; ++i) pm[rb][i] = -1e30f;

  for (int cb = 0; cb < 16; ++cb) {
    bf16x8 kf0 = *(const bf16x8*)(kb + (cb * 16 + fr) * 64 + fk);
    bf16x8 kf1 = *(const bf16x8*)(kb + (cb * 16 + fr) * 64 + 32 + fk);
#pragma unroll
    for (int rb = 0; rb < 4; ++rb) {
      f32x4 s = __builtin_amdgcn_mfma_f32_16x16x32_bf16(qf[rb][0], kf0, z, 0, 0, 0);
      s = __builtin_amdgcn_mfma_f32_16x16x32_bf16(qf[rb][1], kf1, s, 0, 0, 0);
#pragma unroll
      for (int i = 0; i < 4; ++i) pm[rb][i] = fmaxf(pm[rb][i], s[i]);
    }
  }
#pragma unroll
  for (int rb = 0; rb < 4; ++rb)
#pragma unroll
    for (int i = 0; i < 4; ++i) {
      float v = pm[rb][i];
      v = fmaxf(v, __shfl_xor(v, 1));
      v = fmaxf(v, __shfl_xor(v, 2));
      v = fmaxf(v, __shfl_xor(v, 4));
      v = fmaxf(v, __shfl_xor(v, 8));
      pm[rb][i] = v;
    }

  f32x4 oacc[4][4];
  float psum[4][4];
#pragma unroll
  for (int rb = 0; rb < 4; ++rb)
#pragma unroll
    for (int nb = 0; nb < 4; ++nb) oacc[rb][nb] = z;
#pragma unroll
  for (int rb = 0; rb < 4; ++rb)
#pragma unroll
    for (int i = 0; i < 4; ++i) psum[rb][i] = 0.f;

  for (int kb2 = 0; kb2 < 8; ++kb2) {
#pragma unroll
    for (int c2 = 0; c2 < 2; ++c2) {
      int cb = kb2 * 2 + c2;
      bf16x8 kf0 = *(const bf16x8*)(kb + (cb * 16 + fr) * 64 + fk);
      bf16x8 kf1 = *(const bf16x8*)(kb + (cb * 16 + fr) * 64 + 32 + fk);
#pragma unroll
      for (int rb = 0; rb < 4; ++rb) {
        f32x4 s = __builtin_amdgcn_mfma_f32_16x16x32_bf16(qf[rb][0], kf0, z, 0, 0, 0);
        s = __builtin_amdgcn_mfma_f32_16x16x32_bf16(qf[rb][1], kf1, s, 0, 0, 0);
#pragma unroll
        for (int i = 0; i < 4; ++i) {
          float p = __expf(scale * (s[i] - pm[rb][i]));
          psum[rb][i] += p;
          Pw[wave][(rb * 16 + (fg << 2) + i) * 32 + c2 * 16 + fr] = f2bf(p);
        }
      }
    }
    bf16x8 pa[4], vf[4];
#pragma unroll
    for (int rb = 0; rb < 4; ++rb) pa[rb] = *(const bf16x8*)(&Pw[wave][(rb * 16 + fr) * 32 + fk]);
#pragma unroll
    for (int nb = 0; nb < 4; ++nb)
      vf[nb] = *(const bf16x8*)(vb + (nb * 16 + fr) * 256 + kb2 * 32 + fk);
#pragma unroll
    for (int rb = 0; rb < 4; ++rb)
#pragma unroll
      for (int nb = 0; nb < 4; ++nb)
        oacc[rb][nb] = __builtin_amdgcn_mfma_f32_16x16x32_bf16(pa[rb], vf[nb], oacc[rb][nb], 0, 0, 0);
  }

  float rs[4][4];
#pragma unroll
  for (int rb = 0; rb < 4; ++rb)
#pragma unroll
    for (int i = 0; i < 4; ++i) {
      float v = psum[rb][i];
      v += __shfl_xor(v, 1);
      v += __shfl_xor(v, 2);
      v += __shfl_xor(v, 4);
      v += __shfl_xor(v, 8);
      rs[rb][i] = 1.0f / v;
    }

#pragma unroll
  for (int rb = 0; rb < 4; ++rb)
#pragma unroll
    for (int nb = 0; nb < 4; ++nb)
#pragma unroll
      for (int i = 0; i < 4; ++i) {
        int token = b * 256 + qrow0 + rb * 16 + (fg << 2) + i;
        int gcol = h * 64 + nb * 16 + fr;
        o[(size_t)token * DE + gcol] = f2bf(oacc[rb][nb][i] * rs[rb][i]);
      }
}

// ---------------- launch ----------------
extern "C" void kernel_launch(void* const* d_in, const int* in_sizes, int n_in,
                              void* d_out, int out_size, void* d_ws, size_t ws_size,
                              hipStream_t stream) {
  const float* x     = (const float*)d_in[0];
  const float* wq    = (const float*)d_in[1];
  const float* wk    = (const float*)d_in[2];
  const float* wv    = (const float*)d_in[3];
  const float* wproj = (const float*)d_in[4];
  const float* bproj = (const float*)d_in[5];
  const float* w1    = (const float*)d_in[6];
  const float* b1    = (const float*)d_in[7];
  const float* w2    = (const float*)d_in[8];
  const float* b2    = (const float*)d_in[9];
  const float* g1    = (const float*)d_in[10];
  const float* be1   = (const float*)d_in[11];
  const float* g2    = (const float*)d_in[12];
  const float* be2   = (const float*)d_in[13];

  char* ws = (char*)d_ws;
  unsigned short* xln   = (unsigned short*)(ws + 0);
  unsigned short* hbuf  = xln;
  unsigned short* qkv   = (unsigned short*)(ws + 50331648);
  unsigned short* attno = (unsigned short*)(ws + 201326592);
  unsigned short* act   = (unsigned short*)(ws + 50331648);
  float*          x1    = (float*)(ws + 251658240);
  unsigned short* wqkvt = (unsigned short*)(ws + 352321536);
  unsigned short* wprjt = (unsigned short*)(ws + 352321536 + 884736);
  unsigned short* w1t   = (unsigned short*)(ws + 352321536 + 884736 + 294912);
  unsigned short* w2t   = (unsigned short*)(ws + 352321536 + 884736 + 294912 + 1179648);

  qkv_pack<<<(3 * 147456 + 255) / 256, 256, 0, stream>>>(wq, wk, wv, wqkvt);
  pack_t<<<(147456 + 255) / 256, 256, 0, stream>>>(wprjt, wproj, 384, 384);
  pack_t<<<(589824 + 255) / 256, 256, 0, stream>>>(w1t, w1, 384, 1536);
  pack_t<<<(589824 + 255) / 256, 256, 0, stream>>>(w2t, w2, 1536, 384);

  ln_kernel<<<NTOK / 4, 256, 0, stream>>>(x, g1, be1, xln);

  // grids: (M/128) * ntx, ntx = N/128 ; all divisible by 8
  gemm_qkv<<<512 * 9, 256, 0, stream>>>(xln, wqkvt, NTOK, 1152, 384, 9,
                                        nullptr, nullptr, nullptr, qkv);

  attn_kernel<<<1536, 256, 0, stream>>>(qkv, qkv + S_HEAD, qkv + 2 * (size_t)S_HEAD, attno);

  gemm_proj<<<512 * 3, 256, 0, stream>>>(attno, wprjt, NTOK, 384, 384, 3,
                                         bproj, x, x1, nullptr);

  ln_kernel<<<NTOK / 4, 256, 0, stream>>>(x1, g2, be2, hbuf);

  gemm_mlp1<<<512 * 12, 256, 0, stream>>>(hbuf, w1t, NTOK, 1536, 384, 12,
                                          b1, nullptr, nullptr, act);

  gemm_mlp2<<<512 * 3, 256, 0, stream>>>(act, w2t, NTOK, 384, 1536, 3,
                                         b2, x1, (float*)d_out, nullptr);
}

// Round 4
// 559.060 us; speedup vs baseline: 1.2130x; 1.0445x over previous
//
#include <hip/hip_runtime.h>
#include <stdint.h>

#define NTOK 65536          // B*T
#define DE 384
#define QSTR 1280           // padded qkv row stride (1152 -> 1280)

typedef __bf16 bf16x8 __attribute__((ext_vector_type(8)));
typedef float  f32x4 __attribute__((ext_vector_type(4)));
typedef unsigned short u16x8 __attribute__((ext_vector_type(8)));

__device__ __forceinline__ unsigned short f2bf(float f) {
  union { float fl; unsigned u; } a; a.fl = f;
  unsigned r = a.u + 0x7fffu + ((a.u >> 16) & 1u);
  return (unsigned short)(r >> 16);
}

__device__ __forceinline__ void gll16(const void* g, void* l) {
  __builtin_amdgcn_global_load_lds((const __attribute__((address_space(1))) void*)g,
                                   (__attribute__((address_space(3))) void*)l, 16, 0, 0);
}

__device__ __forceinline__ bf16x8 ds128(unsigned addr) {
  bf16x8 r;
  asm volatile("ds_read_b128 %0, %1" : "=v"(r) : "v"(addr));
  return r;
}

// ---------------- weight packing ----------------
__global__ void pack_t(unsigned short* __restrict__ dst, const float* __restrict__ src,
                       int R, int C) {
  int t = blockIdx.x * 256 + threadIdx.x;
  if (t >= R * C) return;
  int r = t / C, c = t - r * C;
  dst[(size_t)c * R + r] = f2bf(src[t]);
}

// Wqkv_t padded [1280][384]: n = which*384 + h*64 + e  (rows >=1152 are zero)
__global__ void qkv_pack(const float* __restrict__ wq, const float* __restrict__ wk,
                         const float* __restrict__ wv, unsigned short* __restrict__ dst) {
  int t = blockIdx.x * 256 + threadIdx.x;
  if (t >= QSTR * 384) return;
  int n = t / 384, k = t - n * 384;
  unsigned short v = 0;
  if (n < 1152) {
    int which = n / 384, r = n - which * 384;
    const float* src = which == 0 ? wq : (which == 1 ? wk : wv);
    int h = r >> 6, e = r & 63;
    v = f2bf(src[h * 24576 + k * 64 + e]);
  }
  dst[t] = v;
}

// ---------------- layernorm (f32 in -> bf16 out), wave per row ----------------
__global__ __launch_bounds__(256) void ln_kernel(const float* __restrict__ x,
                                                 const float* __restrict__ g,
                                                 const float* __restrict__ be,
                                                 unsigned short* __restrict__ out) {
  int wave = threadIdx.x >> 6, lane = threadIdx.x & 63;
  size_t row = (size_t)blockIdx.x * 4 + wave;
  const float* xr = x + row * DE;
  int c0 = lane * 2;
  float2 v0 = *(const float2*)(xr + c0);
  float2 v1 = *(const float2*)(xr + 128 + c0);
  float2 v2 = *(const float2*)(xr + 256 + c0);
  float s  = v0.x + v0.y + v1.x + v1.y + v2.x + v2.y;
  float ss = v0.x*v0.x + v0.y*v0.y + v1.x*v1.x + v1.y*v1.y + v2.x*v2.x + v2.y*v2.y;
#pragma unroll
  for (int m = 1; m < 64; m <<= 1) { s += __shfl_xor(s, m); ss += __shfl_xor(ss, m); }
  float mu = s * (1.0f / 384.0f);
  float rstd = rsqrtf(ss * (1.0f / 384.0f) - mu * mu + 1e-5f);
  unsigned short* orow = out + row * DE;
  {
    float a0 = (v0.x - mu) * rstd * g[c0] + be[c0];
    float a1 = (v0.y - mu) * rstd * g[c0 + 1] + be[c0 + 1];
    *(unsigned*)(orow + c0) = (unsigned)f2bf(a0) | ((unsigned)f2bf(a1) << 16);
  }
  {
    int c = c0 + 128;
    float a0 = (v1.x - mu) * rstd * g[c] + be[c];
    float a1 = (v1.y - mu) * rstd * g[c + 1] + be[c + 1];
    *(unsigned*)(orow + c) = (unsigned)f2bf(a0) | ((unsigned)f2bf(a1) << 16);
  }
  {
    int c = c0 + 256;
    float a0 = (v2.x - mu) * rstd * g[c] + be[c];
    float a1 = (v2.y - mu) * rstd * g[c + 1] + be[c + 1];
    *(unsigned*)(orow + c) = (unsigned)f2bf(a0) | ((unsigned)f2bf(a1) << 16);
  }
}

// ---------------- GEMM core: C[M,N] = A[M,K] @ Bt[N,K]^T ----------------
// BM x BN tile, WM x WN wave grid (8 waves, 512 thr), BK=64, dbuf swizzled LDS,
// counted vmcnt + asm ds_read + lgkmcnt + setprio.
// EPI 0: bf16 natural; EPI 1/3: f32 acc+bias+resid; EPI 2: bf16 relu(acc+bias)
template<int EPI, int BM, int BN, int WM, int WN>
__device__ __forceinline__
void gemm_core(const unsigned short* __restrict__ A, const unsigned short* __restrict__ Bt,
               int M, int N, int K, int ntx,
               const float* __restrict__ bias, const float* __restrict__ resid,
               float* __restrict__ outf, unsigned short* __restrict__ outb) {
  constexpr int T = WM * WN * 64;
  constexpr int MWT = BM / WM, NWT = BN / WN;
  constexpr int MF = MWT / 16, NF = NWT / 16;
  constexpr int MH = MF / 4;           // m-halves of 4 frags each
  constexpr int LA = (BM * 128) / (T * 16);
  constexpr int LB = (BN * 128) / (T * 16);
  __shared__ __align__(16) unsigned short As[2][BM * 64];
  __shared__ __align__(16) unsigned short Bs[2][BN * 64];
  const int tid = threadIdx.x;
  const int wave = tid >> 6, lane = tid & 63;

  const int nwg = gridDim.x;
  const int cpx = nwg >> 3;
  const int wg = (blockIdx.x & 7) * cpx + (blockIdx.x >> 3);
  const int bx = wg % ntx, by = wg / ntx;
  const int mBase = by * BM, nBase = bx * BN;
  const int wmi = wave / WN, wni = wave % WN;
  const int wm = wmi * MWT, wn = wni * NWT;
  const int fr = lane & 15, fg = lane >> 4;

  const unsigned asb = (unsigned)(uintptr_t)&As[0][0];
  const unsigned bsb = (unsigned)(uintptr_t)&Bs[0][0];

  f32x4 acc[MF][NF];
  const f32x4 z = {0.f, 0.f, 0.f, 0.f};
#pragma unroll
  for (int i = 0; i < MF; ++i)
#pragma unroll
    for (int j = 0; j < NF; ++j) acc[i][j] = z;

  auto stage = [&](int buf, int kt) {
#pragma unroll
    for (int i = 0; i < LA; ++i) {
      int Lb = i * (T * 16) + wave * 1024;   // wave-uniform LDS byte base
      int L = Lb + lane * 16;
      int row = L >> 7;
      int col = (((L >> 4) & 7) ^ (row & 7)) << 3;
      gll16(A + (size_t)(mBase + row) * K + kt + col, (unsigned short*)As[buf] + (Lb >> 1));
    }
#pragma unroll
    for (int i = 0; i < LB; ++i) {
      int Lb = i * (T * 16) + wave * 1024;
      int L = Lb + lane * 16;
      int row = L >> 7;
      int col = (((L >> 4) & 7) ^ (row & 7)) << 3;
      gll16(Bt + (size_t)(nBase + row) * K + kt + col, (unsigned short*)Bs[buf] + (Lb >> 1));
    }
  };

  const int NK = K >> 6;
  stage(0, 0);
  for (int t = 0; t < NK; ++t) {
    const int cur = t & 1;
    if (t + 1 < NK) {
      stage(cur ^ 1, (t + 1) << 6);
      if constexpr (LA + LB == 8) asm volatile("s_waitcnt vmcnt(8)" ::: "memory");
      else                        asm volatile("s_waitcnt vmcnt(6)" ::: "memory");
    } else {
      asm volatile("s_waitcnt vmcnt(0)" ::: "memory");
    }
    asm volatile("" ::: "memory");
    __builtin_amdgcn_s_barrier();
    asm volatile("" ::: "memory");

    const unsigned ab = asb + (cur ? (unsigned)(BM * 128) : 0u);
    const unsigned bb = bsb + (cur ? (unsigned)(BN * 128) : 0u);
#pragma unroll
    for (int ks = 0; ks < 2; ++ks) {
      bf16x8 bfr[NF];
#pragma unroll
      for (int nb = 0; nb < NF; ++nb) {
        int row = wn + nb * 16 + fr;
        unsigned byte = (unsigned)(row << 7) + ((unsigned)((ks * 4 + fg) ^ (row & 7)) << 4);
        bfr[nb] = ds128(bb + byte);
      }
#pragma unroll
      for (int mh = 0; mh < MH; ++mh) {
        bf16x8 af[4];
#pragma unroll
        for (int mb = 0; mb < 4; ++mb) {
          int row = wm + (mh * 4 + mb) * 16 + fr;
          unsigned byte = (unsigned)(row << 7) + ((unsigned)((ks * 4 + fg) ^ (row & 7)) << 4);
          af[mb] = ds128(ab + byte);
        }
        asm volatile("s_waitcnt lgkmcnt(0)" ::: "memory");
        __builtin_amdgcn_sched_barrier(0);
        __builtin_amdgcn_s_setprio(1);
#pragma unroll
        for (int mb = 0; mb < 4; ++mb)
#pragma unroll
          for (int nb = 0; nb < NF; ++nb)
            acc[mh * 4 + mb][nb] =
                __builtin_amdgcn_mfma_f32_16x16x32_bf16(af[mb], bfr[nb], acc[mh * 4 + mb][nb], 0, 0, 0);
        __builtin_amdgcn_s_setprio(0);
      }
    }
    asm volatile("" ::: "memory");
    __builtin_amdgcn_s_barrier();
    asm volatile("" ::: "memory");
  }

#pragma unroll
  for (int mb = 0; mb < MF; ++mb) {
#pragma unroll
    for (int nb = 0; nb < NF; ++nb) {
      const int gn = nBase + wn + nb * 16 + fr;
#pragma unroll
      for (int i = 0; i < 4; ++i) {
        const int gm = mBase + wm + mb * 16 + (fg << 2) + i;
        float val = acc[mb][nb][i];
        if (EPI == 0) {
          outb[(size_t)gm * N + gn] = f2bf(val);
        } else if (EPI == 1) {
          size_t idx = (size_t)gm * N + gn;
          outf[idx] = val + bias[gn] + resid[idx];
        } else if (EPI == 2) {
          float r = val + bias[gn];
          outb[(size_t)gm * N + gn] = f2bf(r > 0.f ? r : 0.f);
        } else {
          size_t idx = (size_t)gm * N + gn;
          outf[idx] = val + bias[gn] + resid[idx];
        }
      }
    }
  }
}

__global__ __launch_bounds__(512, 1)
void gemm_qkv(const unsigned short* __restrict__ A, const unsigned short* __restrict__ Bt,
              int M, int N, int K, int ntx, const float* __restrict__ bias,
              const float* __restrict__ resid, float* __restrict__ outf,
              unsigned short* __restrict__ outb) {
  gemm_core<0, 256, 256, 2, 4>(A, Bt, M, N, K, ntx, bias, resid, outf, outb);
}
__global__ __launch_bounds__(512, 1)
void gemm_proj(const unsigned short* __restrict__ A, const unsigned short* __restrict__ Bt,
               int M, int N, int K, int ntx, const float* __restrict__ bias,
               const float* __restrict__ resid, float* __restrict__ outf,
               unsigned short* __restrict__ outb) {
  gemm_core<1, 256, 128, 4, 2>(A, Bt, M, N, K, ntx, bias, resid, outf, outb);
}
__global__ __launch_bounds__(512, 1)
void gemm_mlp1(const unsigned short* __restrict__ A, const unsigned short* __restrict__ Bt,
               int M, int N, int K, int ntx, const float* __restrict__ bias,
               const float* __restrict__ resid, float* __restrict__ outf,
               unsigned short* __restrict__ outb) {
  gemm_core<2, 256, 256, 2, 4>(A, Bt, M, N, K, ntx, bias, resid, outf, outb);
}
__global__ __launch_bounds__(512, 1)
void gemm_mlp2(const unsigned short* __restrict__ A, const unsigned short* __restrict__ Bt,
               int M, int N, int K, int ntx, const float* __restrict__ bias,
               const float* __restrict__ resid, float* __restrict__ outf,
               unsigned short* __restrict__ outb) {
  gemm_core<3, 256, 128, 4, 2>(A, Bt, M, N, K, ntx, bias, resid, outf, outb);
}

// ---------------- attention: one block per (b,h), 4 waves x 64 Q-rows ----------------
// Reads q/k/v from natural [NTOK][1280] layout; V transposed into swizzled LDS once.
__global__ __launch_bounds__(256)
void attn_kernel(const unsigned short* __restrict__ qkvn, unsigned short* __restrict__ o) {
  __shared__ unsigned short Vt[64 * 256];   // V^T [e][s], 16B-slot XOR swizzled
  __shared__ unsigned short Pw[4][64 * 32];
  const int bh = blockIdx.x;
  const int b = bh / 6, h = bh - b * 6;
  const unsigned short* base = qkvn + (size_t)(b * 256) * QSTR;
  const unsigned short* qb = base + h * 64;
  const unsigned short* kbp = base + 384 + h * 64;
  const unsigned short* vbp = base + 768 + h * 64;
  const int wave = threadIdx.x >> 6, lane = threadIdx.x & 63;
  const int fr = lane & 15, fg = lane >> 4;
  const int fk = fg << 3;
  const int qrow0 = wave << 6;
  const float scale = 0.051031036307982884f;  // 1/sqrt(384)
  const f32x4 z = {0.f, 0.f, 0.f, 0.f};

  // stage V^T: thread s reads V row s (64 feats), writes swizzled column
  {
    const int s = threadIdx.x;
    u16x8 v8[8];
#pragma unroll
    for (int j = 0; j < 8; ++j)
      v8[j] = *(const u16x8*)(vbp + (size_t)s * QSTR + j * 8);
#pragma unroll
    for (int e = 0; e < 64; ++e)
      Vt[(e << 8) + (s ^ ((e & 7) << 3))] = v8[e >> 3][e & 7];
  }
  __syncthreads();

  bf16x8 qf[4][2];
#pragma unroll
  for (int rb = 0; rb < 4; ++rb)
#pragma unroll
    for (int ks = 0; ks < 2; ++ks)
      qf[rb][ks] = *(const bf16x8*)(qb + (size_t)(qrow0 + rb * 16 + fr) * QSTR + ks * 32 + fk);

  float pm[4][4];
#pragma unroll
  for (int rb = 0; rb < 4; ++rb)
#pragma unroll
    for (int i = 0; i < 4; ++i) pm[rb][i] = -1e30f;

  for (int cb = 0; cb < 16; ++cb) {
    bf16x8 kf0 = *(const bf16x8*)(kbp + (size_t)(cb * 16 + fr) * QSTR + fk);
    bf16x8 kf1 = *(const bf16x8*)(kbp + (size_t)(cb * 16 + fr) * QSTR + 32 + fk);
#pragma unroll
    for (int rb = 0; rb < 4; ++rb) {
      f32x4 s = __builtin_amdgcn_mfma_f32_16x16x32_bf16(qf[rb][0], kf0, z, 0, 0, 0);
      s = __builtin_amdgcn_mfma_f32_16x16x32_bf16(qf[rb][1], kf1, s, 0, 0, 0);
#pragma unroll
      for (int i = 0; i < 4; ++i) pm[rb][i] = fmaxf(pm[rb][i], s[i]);
    }
  }
#pragma unroll
  for (int rb = 0; rb < 4; ++rb)
#pragma unroll
    for (int i = 0; i < 4; ++i) {
      float v = pm[rb][i];
      v = fmaxf(v, __shfl_xor(v, 1));
      v = fmaxf(v, __shfl_xor(v, 2));
      v = fmaxf(v, __shfl_xor(v, 4));
      v = fmaxf(v, __shfl_xor(v, 8));
      pm[rb][i] = v;
    }

  f32x4 oacc[4][4];
  float psum[4][4];
#pragma unroll
  for (int rb = 0; rb < 4; ++rb)
#pragma unroll
    for (int nb = 0; nb < 4; ++nb) oacc[rb][nb] = z;
#pragma unroll
  for (int rb = 0; rb < 4; ++rb)
#pragma unroll
    for (int i = 0; i < 4; ++i) psum[rb][i] = 0.f;

  for (int kb2 = 0; kb2 < 8; ++kb2) {
#pragma unroll
    for (int c2 = 0; c2 < 2; ++c2) {
      int cb = kb2 * 2 + c2;
      bf16x8 kf0 = *(const bf16x8*)(kbp + (size_t)(cb * 16 + fr) * QSTR + fk);
      bf16x8 kf1 = *(const bf16x8*)(kbp + (size_t)(cb * 16 + fr) * QSTR + 32 + fk);
#pragma unroll
      for (int rb = 0; rb < 4; ++rb) {
        f32x4 s = __builtin_amdgcn_mfma_f32_16x16x32_bf16(qf[rb][0], kf0, z, 0, 0, 0);
        s = __builtin_amdgcn_mfma_f32_16x16x32_bf16(qf[rb][1], kf1, s, 0, 0, 0);
#pragma unroll
        for (int i = 0; i < 4; ++i) {
          float p = __expf(scale * (s[i] - pm[rb][i]));
          psum[rb][i] += p;
          Pw[wave][(rb * 16 + (fg << 2) + i) * 32 + c2 * 16 + fr] = f2bf(p);
        }
      }
    }
    bf16x8 pa[4], vf[4];
#pragma unroll
    for (int rb = 0; rb < 4; ++rb) pa[rb] = *(const bf16x8*)(&Pw[wave][(rb * 16 + fr) * 32 + fk]);
#pragma unroll
    for (int nb = 0; nb < 4; ++nb) {
      int e = nb * 16 + fr;
      vf[nb] = *(const bf16x8*)(&Vt[(e << 8) + ((kb2 * 32 + fk) ^ ((e & 7) << 3))]);
    }
#pragma unroll
    for (int rb = 0; rb < 4; ++rb)
#pragma unroll
      for (int nb = 0; nb < 4; ++nb)
        oacc[rb][nb] = __builtin_amdgcn_mfma_f32_16x16x32_bf16(pa[rb], vf[nb], oacc[rb][nb], 0, 0, 0);
  }

  float rs[4][4];
#pragma unroll
  for (int rb = 0; rb < 4; ++rb)
#pragma unroll
    for (int i = 0; i < 4; ++i) {
      float v = psum[rb][i];
      v += __shfl_xor(v, 1);
      v += __shfl_xor(v, 2);
      v += __shfl_xor(v, 4);
      v += __shfl_xor(v, 8);
      rs[rb][i] = 1.0f / v;
    }

#pragma unroll
  for (int rb = 0; rb < 4; ++rb)
#pragma unroll
    for (int nb = 0; nb < 4; ++nb)
#pragma unroll
      for (int i = 0; i < 4; ++i) {
        int token = b * 256 + qrow0 + rb * 16 + (fg << 2) + i;
        int gcol = h * 64 + nb * 16 + fr;
        o[(size_t)token * DE + gcol] = f2bf(oacc[rb][nb][i] * rs[rb][i]);
      }
}

// ---------------- launch ----------------
extern "C" void kernel_launch(void* const* d_in, const int* in_sizes, int n_in,
                              void* d_out, int out_size, void* d_ws, size_t ws_size,
                              hipStream_t stream) {
  const float* x     = (const float*)d_in[0];
  const float* wq    = (const float*)d_in[1];
  const float* wk    = (const float*)d_in[2];
  const float* wv    = (const float*)d_in[3];
  const float* wproj = (const float*)d_in[4];
  const float* bproj = (const float*)d_in[5];
  const float* w1    = (const float*)d_in[6];
  const float* b1    = (const float*)d_in[7];
  const float* w2    = (const float*)d_in[8];
  const float* b2    = (const float*)d_in[9];
  const float* g1    = (const float*)d_in[10];
  const float* be1   = (const float*)d_in[11];
  const float* g2    = (const float*)d_in[12];
  const float* be2   = (const float*)d_in[13];

  char* ws = (char*)d_ws;
  // lifetime-overlapped layout (bytes):
  //  xln   @0           [50.3MB]  dead after qkv-gemm
  //  x1    @0           [100.7MB] f32, proj out, live till mlp2 (overlaps dead xln)
  //  qkvn  @50331648    [167.8MB] dead after attn
  //  hbuf  @100663296   [50.3MB]  LN2 out (inside dead qkvn, past live x1)
  //  attno @218103808   [50.3MB]  attn out (right after qkvn), dead after proj
  //  act   @150994944   [201.3MB] mlp1 out (over dead qkvn tail + dead attno)
  //  weights @352321536
  unsigned short* xln   = (unsigned short*)(ws + 0);
  float*          x1    = (float*)(ws + 0);
  unsigned short* qkvn  = (unsigned short*)(ws + 50331648);
  unsigned short* hbuf  = (unsigned short*)(ws + 100663296);
  unsigned short* act   = (unsigned short*)(ws + 150994944);
  unsigned short* attno = (unsigned short*)(ws + 218103808);
  unsigned short* wqkvt = (unsigned short*)(ws + 352321536);
  unsigned short* wprjt = (unsigned short*)(ws + 352321536 + 983040);
  unsigned short* w1t   = (unsigned short*)(ws + 352321536 + 983040 + 294912);
  unsigned short* w2t   = (unsigned short*)(ws + 352321536 + 983040 + 294912 + 1179648);

  qkv_pack<<<(QSTR * 384 + 255) / 256, 256, 0, stream>>>(wq, wk, wv, wqkvt);
  pack_t<<<(147456 + 255) / 256, 256, 0, stream>>>(wprjt, wproj, 384, 384);
  pack_t<<<(589824 + 255) / 256, 256, 0, stream>>>(w1t, w1, 384, 1536);
  pack_t<<<(589824 + 255) / 256, 256, 0, stream>>>(w2t, w2, 1536, 384);

  ln_kernel<<<NTOK / 4, 256, 0, stream>>>(x, g1, be1, xln);

  // grids: ntx * (M/256); all divisible by 8
  gemm_qkv<<<5 * 256, 512, 0, stream>>>(xln, wqkvt, NTOK, QSTR, 384, 5,
                                        nullptr, nullptr, nullptr, qkvn);

  attn_kernel<<<1536, 256, 0, stream>>>(qkvn, attno);

  gemm_proj<<<3 * 256, 512, 0, stream>>>(attno, wprjt, NTOK, 384, 384, 3,
                                         bproj, x, x1, nullptr);

  ln_kernel<<<NTOK / 4, 256, 0, stream>>>(x1, g2, be2, hbuf);

  gemm_mlp1<<<6 * 256, 512, 0, stream>>>(hbuf, w1t, NTOK, 1536, 384, 6,
                                         b1, nullptr, nullptr, act);

  gemm_mlp2<<<3 * 256, 512, 0, stream>>>(act, w2t, NTOK, 384, 1536, 3,
                                         b2, x1, (float*)d_out, nullptr);
}